// Round 7
// baseline (122.104 us; speedup 1.0000x reference)
//
#include <hip/hip_runtime.h>
#include <math.h>

// ---- problem constants ----
#define WAV_N     262144
#define HOP       128
#define MIN_WIN   16699
#define LEFT      24418            // (65536 - 16699)/2
#define T_FRAMES  2049
#define N_BINS    96
#define N_CQCC    20
#define F_COMP    192              // 96 bins x {lo,hi}
#define NF        576              // 192 comps x 3 Hann planes
#define NBLK      2179             // 128-sample chunks covering padded signal
#define NBP       2240             // padded b-dim for QF/QP rows (= 35*64)
#define PARTLEN   59               // 16699 - 130*128
#define FULLBLK   130
#define XS_VALID  278843           // 2048*128 + 16699
#define TWOPI     6.283185307179586f

// ---- chunk kernel tiling: 256 thr = 16 f-pairs x 16 b-groups(4 b each) ----
#define BT   64
#define FTW  32
#define JC   32
#define AST  68                    // A_lds row stride (272 B, 16B-aligned)

// ---- workspace layout (bytes) ----
#define WS_QF   0                  // 576*2240*8 = 10,321,920  qf (full-chunk sums)
#define WS_QP   10321920           // 10,321,920               qp (j<59 partials)
#define WS_VT   20643840           // 2049*576*8 = 9,441,792   rotated V [t][f]
#define WS_CQ   30085632           // 2049*20*4  =   163,920
#define WS_SUMS 30249552           // 40 doubles

// f = plane*192 + c; c = bin*2 + hi; replicate reference f32 arithmetic for floor()
__device__ __forceinline__ void f_to_fi_sigma(int f, int& fi, int& sigma) {
    int plane = f / 192;
    int c = f - plane * 192;
    int bin = c >> 1, hi = c & 1;
    float e    = (float)bin / 24.0f;
    float fb   = 32.7f * exp2f(e);
    float idxf = fb / 8000.0f * 32768.0f;
    fi = (int)idxf + hi;
    sigma = (plane == 0) ? 0 : (plane == 1 ? 1 : -1);
}

// QF[f][b] = e^{-i w0} sum_{j<128} xs[128b+j] E[j][f];  QP = j<59 version
__global__ __launch_bounds__(256) void k_chunk(const float* __restrict__ wav,
                                               float2* __restrict__ QF,
                                               float2* __restrict__ QP) {
    __shared__ float A_lds[JC * AST];              // 8704 B
    int tid = threadIdx.x;
    int b0 = blockIdx.x * BT;
    int f0 = blockIdx.y * FTW;
    int ftp = tid & 15;                            // f-pair index (32 f per block)
    int bg  = tid >> 4;                            // 16 groups x 4 b
    int bb  = b0 + bg * 4;

    int fi[2], sg[2];
    f_to_fi_sigma(f0 + 2 * ftp,     fi[0], sg[0]);
    f_to_fi_sigma(f0 + 2 * ftp + 1, fi[1], sg[1]);

    // per-j rotator step D[f] = e^{-2*pi*i*(fi/65536 - sg/W)}
    float Dr[2], Di[2];
    #pragma unroll
    for (int h = 0; h < 2; ++h) {
        float fr = (float)fi[h] * (1.0f / 65536.0f)
                 - (float)sg[h] * (1.0f / (float)MIN_WIN);
        fr -= rintf(fr);
        float sn, cs; __sincosf(TWOPI * fr, &sn, &cs);
        Dr[h] = cs; Di[h] = -sn;
    }

    float xr[2][4], xi[2][4], pr[2][4], pi[2][4];
    #pragma unroll
    for (int h = 0; h < 2; ++h)
        #pragma unroll
        for (int i = 0; i < 4; ++i) { xr[h][i] = 0.f; xi[h][i] = 0.f; }

    for (int jc = 0; jc < 4; ++jc) {
        int jbase = jc * JC;
        __syncthreads();
        // stage A chunk: A_lds[j][bl] = xs[128*(b0+bl) + jbase + j], reflect from wav
        #pragma unroll
        for (int i = 0; i < 8; ++i) {
            int m = i * 256 + tid;                 // 32j x 64bl
            int j = m & 31, bl = m >> 5;
            int s = 128 * (b0 + bl) + jbase + j;
            float v = 0.0f;
            if (s < XS_VALID) {
                int w = s - 8350;                  // s + LEFT - 32768
                if (w < 0) w = -w;
                if (w >= WAV_N) w = 2 * WAV_N - 2 - w;
                v = wav[w];
            }
            A_lds[j * AST + bl] = v;
        }
        __syncthreads();
        // anchor rotators at j = jbase (exact integer phase -- no drift across chunks)
        float Wr[2], Wi[2];
        #pragma unroll
        for (int h = 0; h < 2; ++h) {
            float fr = (float)((jbase * fi[h]) & 65535) * (1.0f / 65536.0f)
                     - (float)sg[h] * (float)jbase * (1.0f / (float)MIN_WIN);
            fr -= rintf(fr);
            float sn, cs; __sincosf(TWOPI * fr, &sn, &cs);
            Wr[h] = cs; Wi[h] = -sn;
        }
        #pragma unroll 8
        for (int j32 = 0; j32 < JC; ++j32) {
            if (jc == 1 && j32 == PARTLEN - 32) {  // snapshot partial sum (j<59)
                #pragma unroll
                for (int h = 0; h < 2; ++h)
                    #pragma unroll
                    for (int i = 0; i < 4; ++i) { pr[h][i] = xr[h][i]; pi[h][i] = xi[h][i]; }
            }
            float4 a = *(const float4*)&A_lds[j32 * AST + bg * 4];
            const float aa[4] = {a.x, a.y, a.z, a.w};
            #pragma unroll
            for (int h = 0; h < 2; ++h) {
                float wr = Wr[h], wi = Wi[h];
                #pragma unroll
                for (int i = 0; i < 4; ++i) {
                    xr[h][i] = fmaf(aa[i], wr, xr[h][i]);
                    xi[h][i] = fmaf(aa[i], wi, xi[h][i]);
                }
                Wr[h] = wr * Dr[h] - wi * Di[h];
                Wi[h] = wr * Di[h] + wi * Dr[h];
            }
        }
    }

    // apply e^{-i w0(b,f)} and store; b>=NBLK lands in row pad
    #pragma unroll
    for (int h = 0; h < 2; ++h) {
        int f = f0 + 2 * ftp + h;
        float2* dstF = QF + (size_t)f * NBP + bb;
        float2* dstP = QP + (size_t)f * NBP + bb;
        #pragma unroll
        for (int i = 0; i < 4; ++i) {
            int b = bb + i;
            unsigned ph = ((unsigned)fi[h] * (unsigned)(LEFT + 128 * b)) & 65535u;
            float frf = (float)ph * (1.0f / 65536.0f)
                      - (float)sg[h] * (float)((128 * b) % MIN_WIN) * (1.0f / (float)MIN_WIN);
            frf -= rintf(frf);
            float sn, cs; __sincosf(TWOPI * frf, &sn, &cs);
            dstF[i] = make_float2(xr[h][i] * cs + xi[h][i] * sn,
                                  xi[h][i] * cs - xr[h][i] * sn);
            dstP[i] = make_float2(pr[h][i] * cs + pi[h][i] * sn,
                                  pi[h][i] * cs - pr[h][i] * sn);
        }
    }
}

// one block per f (576 blocks): fp64 scan of QF column, U = G[t+130]-G[t]+QP[t+130],
// rotate by e^{+i tau}, scatter V into VT[t][f]
#define SEG 9                      // 256*9 >= 2179
__global__ __launch_bounds__(256) void k_scan(const float2* __restrict__ QF,
                                              const float2* __restrict__ QP,
                                              float2* __restrict__ VT,
                                              double* __restrict__ sums) {
    __shared__ float2 col[NBLK];       // 17,432 B
    __shared__ double2 wsum[4];
    int tid = threadIdx.x;
    int f = blockIdx.x;
    if (f == 0 && tid < 40) sums[tid] = 0.0;   // zero stats accumulators

    const float2* g = QF + (size_t)f * NBP;
    #pragma unroll
    for (int k = 0; k < SEG; ++k) {
        int idx = k * 256 + tid;
        if (idx < NBLK) col[idx] = g[idx];
    }
    __syncthreads();
    int s0 = tid * SEG, s1 = min(s0 + SEG, NBLK);
    double sr = 0.0, si = 0.0;
    for (int i = s0; i < s1; ++i) { sr += col[i].x; si += col[i].y; }
    double r = sr, im = si;
    #pragma unroll
    for (int off = 1; off < 64; off <<= 1) {
        double prx = __shfl_up(r, off);
        double piy = __shfl_up(im, off);
        if ((tid & 63) >= off) { r += prx; im += piy; }
    }
    if ((tid & 63) == 63) wsum[tid >> 6] = make_double2(r, im);
    __syncthreads();
    double basr = 0.0, basi = 0.0;
    int w = tid >> 6;
    for (int ww = 0; ww < w; ++ww) { basr += wsum[ww].x; basi += wsum[ww].y; }
    double gr = basr + r - sr, gi = basi + im - si;   // exclusive prefix at s0
    for (int i = s0; i < s1; ++i) {
        float qx = col[i].x, qy = col[i].y;
        col[i].x = (float)gr; col[i].y = (float)gi;
        gr += qx; gi += qy;
    }
    __syncthreads();
    int fi_, sg_; f_to_fi_sigma(f, fi_, sg_);
    #pragma unroll
    for (int k = 0; k < SEG; ++k) {
        int t = k * 256 + tid;
        if (t < T_FRAMES) {
            float2 g0 = col[t];
            float2 g1 = col[t + FULLBLK];
            float2 qp = QP[(size_t)f * NBP + t + FULLBLK];   // coalesced
            float ur = g1.x - g0.x + qp.x;
            float ui = g1.y - g0.y + qp.y;
            unsigned ph = ((unsigned)fi_ * 128u * (unsigned)t) & 65535u;
            float frf = (float)ph * (1.0f / 65536.0f)
                      - (float)sg_ * (float)((128 * t) % MIN_WIN) * (1.0f / (float)MIN_WIN);
            frf -= rintf(frf);
            float sn, cs;
            __sincosf(TWOPI * frf, &sn, &cs);
            VT[(size_t)t * NF + f] = make_float2(ur * cs - ui * sn,
                                                 ur * sn + ui * cs);
        }
    }
}

// 8 frames/block: fold 3 Hann planes (coalesced VT reads) -> power -> interp -> log
// -> DCT; fp64 atomic stats partials
__global__ __launch_bounds__(256) void k_cqt(const float2* __restrict__ VT,
                                             float* __restrict__ cq,
                                             double* __restrict__ sums) {
    __shared__ float dctm[N_CQCC * N_BINS];  // 7680 B
    __shared__ float2 sc[8][F_COMP];         // 12,288 B
    __shared__ float lg[8][N_BINS];          // 3072 B
    __shared__ float cqv[8][N_CQCC];         // 640 B
    int tid = threadIdx.x;
    int tb = blockIdx.x * 8;
    for (int idx = tid; idx < N_CQCC * N_BINS; idx += 256) {
        int k = idx / N_BINS, b = idx - k * N_BINS;
        dctm[idx] = cosf((float)M_PI * (float)(k * (2 * b + 1)) / 192.0f);
    }
    // fold planes: coalesced reads (consecutive tid -> consecutive f)
    for (int idx = tid; idx < 8 * F_COMP; idx += 256) {
        int lt = idx / F_COMP, c = idx - lt * F_COMP;
        int t = tb + lt;
        float2 v = make_float2(0.f, 0.f);
        if (t < T_FRAMES) {
            const float2* row = VT + (size_t)t * NF;
            float2 v0 = row[c], v1 = row[192 + c], v2 = row[384 + c];
            v = make_float2(0.5f * v0.x - 0.25f * (v1.x + v2.x),
                            0.5f * v0.y - 0.25f * (v1.y + v2.y));
        }
        sc[lt][c] = v;
    }
    __syncthreads();
    for (int idx = tid; idx < 8 * N_BINS; idx += 256) {
        int lt = idx / N_BINS, b = idx - lt * N_BINS;
        float2 lo = sc[lt][2 * b], hi = sc[lt][2 * b + 1];
        float pl = lo.x * lo.x + lo.y * lo.y;
        float ph = hi.x * hi.x + hi.y * hi.y;
        float e    = (float)b / 24.0f;
        float fb   = 32.7f * exp2f(e);
        float idxf = fb / 8000.0f * 32768.0f;
        float alpha = idxf - (float)((int)idxf);
        float p = (1.0f - alpha) * pl + alpha * ph;
        lg[lt][b] = logf(fmaxf(p, 1e-8f));
    }
    __syncthreads();
    if (tid < 8 * N_CQCC) {
        int lt = tid / N_CQCC, k = tid - lt * N_CQCC;
        int t = tb + lt;
        float s = 0.0f;
        #pragma unroll 4
        for (int b = 0; b < N_BINS; ++b) s += dctm[k * N_BINS + b] * lg[lt][b];
        cqv[lt][k] = (t < T_FRAMES) ? s : 0.0f;
        if (t < T_FRAMES) cq[t * N_CQCC + k] = s;
    }
    __syncthreads();
    if (tid < N_CQCC) {
        double s1 = 0.0, s2 = 0.0;
        #pragma unroll
        for (int lt = 0; lt < 8; ++lt) {
            if (tb + lt < T_FRAMES) {
                double v = (double)cqv[lt][tid];
                s1 += v; s2 += v * v;
            }
        }
        atomicAdd(&sums[tid], s1);
        atomicAdd(&sums[N_CQCC + tid], s2);
    }
}

__device__ __forceinline__ int clampT(int v) {
    return v < 0 ? 0 : (v > T_FRAMES - 1 ? T_FRAMES - 1 : v);
}

// normalize + delta + delta-delta; mean/inv derived inline from fp64 sums
__global__ void k_final(const float* __restrict__ cq, const double* __restrict__ sums,
                        float* __restrict__ out) {
    int gid = blockIdx.x * blockDim.x + threadIdx.x;
    if (gid >= T_FRAMES * N_CQCC) return;
    int t = gid / N_CQCC;
    int k = gid - t * N_CQCC;
    double S1 = sums[k], S2 = sums[N_CQCC + k];
    double md = S1 / (double)T_FRAMES;
    double var = (S2 - S1 * md) / (double)(T_FRAMES - 1);
    double sd = sqrt(var > 0.0 ? var : 0.0);
    float m = (float)md;
    float iv = (float)(1.0 / (sd + 1e-8));
    float cv[9];
    #pragma unroll
    for (int j = 0; j < 9; ++j)
        cv[j] = (cq[clampT(t + j - 4) * N_CQCC + k] - m) * iv;
    float dv[5];
    #pragma unroll
    for (int o = -2; o <= 2; ++o) {
        int p = clampT(t + o);
        int h1 = clampT(p + 1) - t, l1 = clampT(p - 1) - t;
        int h2 = clampT(p + 2) - t, l2 = clampT(p - 2) - t;
        dv[o + 2] = ((cv[h1 + 4] - cv[l1 + 4]) + 2.0f * (cv[h2 + 4] - cv[l2 + 4])) * 0.1f;
    }
    out[t * 60 + k]      = cv[4];
    out[t * 60 + 20 + k] = dv[2];
    out[t * 60 + 40 + k] = (dv[3] - dv[1] + 2.0f * (dv[4] - dv[0])) * 0.1f;
}

extern "C" void kernel_launch(void* const* d_in, const int* in_sizes, int n_in,
                              void* d_out, int out_size, void* d_ws, size_t ws_size,
                              hipStream_t stream) {
    const float* wav = (const float*)d_in[0];
    float* out = (float*)d_out;
    char* ws = (char*)d_ws;
    float2* QF   = (float2*)(ws + WS_QF);
    float2* QP   = (float2*)(ws + WS_QP);
    float2* VT   = (float2*)(ws + WS_VT);
    float*  cq   = (float*)(ws + WS_CQ);
    double* sums = (double*)(ws + WS_SUMS);

    k_chunk<<<dim3(NBP / BT, NF / FTW), 256, 0, stream>>>(wav, QF, QP);
    k_scan<<<NF, 256, 0, stream>>>(QF, QP, VT, sums);
    k_cqt<<<(T_FRAMES + 7) / 8, 256, 0, stream>>>(VT, cq, sums);
    k_final<<<(T_FRAMES * N_CQCC + 255) / 256, 256, 0, stream>>>(cq, sums, out);
}

// Round 8
// 114.793 us; speedup vs baseline: 1.0637x; 1.0637x over previous
//
#include <hip/hip_runtime.h>
#include <math.h>

// ---- problem constants ----
#define WAV_N     262144
#define HOP       128
#define MIN_WIN   16699
#define LEFT      24418            // (65536 - 16699)/2
#define T_FRAMES  2049
#define N_BINS    96
#define N_CQCC    20
#define F_COMP    192              // 96 bins x {lo,hi}
#define NF        576              // 192 comps x 3 Hann planes
#define NBLK      2179             // 128-sample chunks covering padded signal
#define NBP       2240             // padded b-dim for QFP rows (= 35*64)
#define PARTLEN   59               // 16699 - 130*128
#define FULLBLK   130
#define XS_VALID  278843           // 2048*128 + 16699
#define TWOPI     6.283185307179586f

// ---- chunk kernel tiling: 256 thr = 16 f-pairs x 16 b-groups(4 b each) ----
#define BT   64
#define FTW  32
#define JC   32
#define AST  68                    // A_lds row stride (272 B, 16B-aligned)

// ---- workspace layout (bytes) ----
#define WS_QFP  0                  // 576*2240*16 = 20,643,840  float4(qf.re,qf.im,qp.re,qp.im)
#define WS_SC   20643840           // 192*2056*8  =  3,158,016  folded spectrum [c][t]
#define WS_CQ   23801856           // 2049*20*4   =    163,920
#define WS_SUMS 23965776           // 40 doubles
#define SCP     2056               // Sc row stride (float2 units)

// f = plane*192 + c; c = bin*2 + hi; replicate reference f32 arithmetic for floor()
__device__ __forceinline__ void f_to_fi_sigma(int f, int& fi, int& sigma) {
    int plane = f / 192;
    int c = f - plane * 192;
    int bin = c >> 1, hi = c & 1;
    float e    = (float)bin / 24.0f;
    float fb   = 32.7f * exp2f(e);
    float idxf = fb / 8000.0f * 32768.0f;
    fi = (int)idxf + hi;
    sigma = (plane == 0) ? 0 : (plane == 1 ? 1 : -1);
}

// QFP[f][b] = (qf, qp): qf = e^{-i w0} sum_{j<128} xs[128b+j] E[j][f], qp = j<59 version
__global__ __launch_bounds__(256) void k_chunk(const float* __restrict__ wav,
                                               float4* __restrict__ QFP) {
    __shared__ float A_lds[JC * AST];              // 8704 B
    int tid = threadIdx.x;
    int b0 = blockIdx.x * BT;
    int f0 = blockIdx.y * FTW;
    int ftp = tid & 15;                            // f-pair index (32 f per block)
    int bg  = tid >> 4;                            // 16 groups x 4 b
    int bb  = b0 + bg * 4;

    int fi[2], sg[2];
    f_to_fi_sigma(f0 + 2 * ftp,     fi[0], sg[0]);
    f_to_fi_sigma(f0 + 2 * ftp + 1, fi[1], sg[1]);

    // per-j rotator step D[f] = e^{-2*pi*i*(fi/65536 - sg/W)}
    float Dr[2], Di[2];
    #pragma unroll
    for (int h = 0; h < 2; ++h) {
        float fr = (float)fi[h] * (1.0f / 65536.0f)
                 - (float)sg[h] * (1.0f / (float)MIN_WIN);
        fr -= rintf(fr);
        float sn, cs; __sincosf(TWOPI * fr, &sn, &cs);
        Dr[h] = cs; Di[h] = -sn;
    }

    float xr[2][4], xi[2][4], pr[2][4], pi[2][4];
    #pragma unroll
    for (int h = 0; h < 2; ++h)
        #pragma unroll
        for (int i = 0; i < 4; ++i) { xr[h][i] = 0.f; xi[h][i] = 0.f; }

    for (int jc = 0; jc < 4; ++jc) {
        int jbase = jc * JC;
        __syncthreads();
        // stage A chunk: A_lds[j][bl] = xs[128*(b0+bl) + jbase + j], reflect from wav
        #pragma unroll
        for (int i = 0; i < 8; ++i) {
            int m = i * 256 + tid;                 // 32j x 64bl
            int j = m & 31, bl = m >> 5;
            int s = 128 * (b0 + bl) + jbase + j;
            float v = 0.0f;
            if (s < XS_VALID) {
                int w = s - 8350;                  // s + LEFT - 32768
                if (w < 0) w = -w;
                if (w >= WAV_N) w = 2 * WAV_N - 2 - w;
                v = wav[w];
            }
            A_lds[j * AST + bl] = v;
        }
        __syncthreads();
        // anchor rotators at j = jbase (exact integer phase -- no drift across chunks)
        float Wr[2], Wi[2];
        #pragma unroll
        for (int h = 0; h < 2; ++h) {
            float fr = (float)((jbase * fi[h]) & 65535) * (1.0f / 65536.0f)
                     - (float)sg[h] * (float)jbase * (1.0f / (float)MIN_WIN);
            fr -= rintf(fr);
            float sn, cs; __sincosf(TWOPI * fr, &sn, &cs);
            Wr[h] = cs; Wi[h] = -sn;
        }
        #pragma unroll 8
        for (int j32 = 0; j32 < JC; ++j32) {
            if (jc == 1 && j32 == PARTLEN - 32) {  // snapshot partial sum (j<59)
                #pragma unroll
                for (int h = 0; h < 2; ++h)
                    #pragma unroll
                    for (int i = 0; i < 4; ++i) { pr[h][i] = xr[h][i]; pi[h][i] = xi[h][i]; }
            }
            float4 a = *(const float4*)&A_lds[j32 * AST + bg * 4];
            const float aa[4] = {a.x, a.y, a.z, a.w};
            #pragma unroll
            for (int h = 0; h < 2; ++h) {
                float wr = Wr[h], wi = Wi[h];
                #pragma unroll
                for (int i = 0; i < 4; ++i) {
                    xr[h][i] = fmaf(aa[i], wr, xr[h][i]);
                    xi[h][i] = fmaf(aa[i], wi, xi[h][i]);
                }
                Wr[h] = wr * Dr[h] - wi * Di[h];
                Wi[h] = wr * Di[h] + wi * Dr[h];
            }
        }
    }

    // apply e^{-i w0(b,f)} and store (qf, qp) interleaved; b>=NBLK lands in row pad
    #pragma unroll
    for (int h = 0; h < 2; ++h) {
        int f = f0 + 2 * ftp + h;
        float4* dst = QFP + (size_t)f * NBP + bb;
        #pragma unroll
        for (int i = 0; i < 4; ++i) {
            int b = bb + i;
            unsigned ph = ((unsigned)fi[h] * (unsigned)(LEFT + 128 * b)) & 65535u;
            float frf = (float)ph * (1.0f / 65536.0f)
                      - (float)sg[h] * (float)((128 * b) % MIN_WIN) * (1.0f / (float)MIN_WIN);
            frf -= rintf(frf);
            float sn, cs; __sincosf(TWOPI * frf, &sn, &cs);
            dst[i] = make_float4(xr[h][i] * cs + xi[h][i] * sn,
                                 xi[h][i] * cs - xr[h][i] * sn,
                                 pr[h][i] * cs + pi[h][i] * sn,
                                 pi[h][i] * cs - pr[h][i] * sn);
        }
    }
}

// one block per component c: all 3 Hann-plane columns processed CONCURRENTLY
// (one load phase, one fused triple fp64 scan, one combine) -- r6's serial
// 3-plane loop was 12 dependent phases at 0.75 blocks/CU.
// U = G[t+130]-G[t]+qp[t+130]; rotate by e^{+i tau}; fold 0.5/-0.25/-0.25; Sc[c][t].
#define SEG 9                      // 256*9 >= 2179
__global__ __launch_bounds__(256) void k_scan(const float4* __restrict__ QFP,
                                              float2* __restrict__ Sc,
                                              double* __restrict__ sums) {
    __shared__ float2 col[3 * NBLK];   // 52,296 B
    __shared__ double2 wsum[3][4];
    int tid = threadIdx.x;
    int c = blockIdx.x;
    if (c == 0 && tid < 40) sums[tid] = 0.0;   // zero stats accumulators

    // load .xy (qf) of all 3 plane columns -- 27 independent strided loads
    const float2* base = (const float2*)QFP;
    #pragma unroll
    for (int p = 0; p < 3; ++p) {
        size_t foff = (size_t)(p * 192 + c) * NBP;
        #pragma unroll
        for (int k = 0; k < SEG; ++k) {
            int idx = k * 256 + tid;
            if (idx < NBLK) col[p * NBLK + idx] = base[2 * (foff + idx)];
        }
    }
    __syncthreads();

    int s0 = tid * SEG, s1 = min(s0 + SEG, NBLK);
    double sr[3] = {0, 0, 0}, si[3] = {0, 0, 0};
    #pragma unroll
    for (int p = 0; p < 3; ++p)
        for (int i = s0; i < s1; ++i) {
            sr[p] += col[p * NBLK + i].x;
            si[p] += col[p * NBLK + i].y;
        }
    double r[3], im[3];
    #pragma unroll
    for (int p = 0; p < 3; ++p) { r[p] = sr[p]; im[p] = si[p]; }
    #pragma unroll
    for (int off = 1; off < 64; off <<= 1) {
        #pragma unroll
        for (int p = 0; p < 3; ++p) {
            double prx = __shfl_up(r[p], off);
            double piy = __shfl_up(im[p], off);
            if ((tid & 63) >= off) { r[p] += prx; im[p] += piy; }
        }
    }
    if ((tid & 63) == 63) {
        #pragma unroll
        for (int p = 0; p < 3; ++p) wsum[p][tid >> 6] = make_double2(r[p], im[p]);
    }
    __syncthreads();
    int w = tid >> 6;
    double gr[3], gi[3];
    #pragma unroll
    for (int p = 0; p < 3; ++p) {
        double basr = 0.0, basi = 0.0;
        for (int ww = 0; ww < w; ++ww) { basr += wsum[p][ww].x; basi += wsum[p][ww].y; }
        gr[p] = basr + r[p] - sr[p];       // exclusive prefix at s0
        gi[p] = basi + im[p] - si[p];
    }
    for (int i = s0; i < s1; ++i) {
        #pragma unroll
        for (int p = 0; p < 3; ++p) {
            float2 old = col[p * NBLK + i];
            col[p * NBLK + i] = make_float2((float)gr[p], (float)gi[p]);
            gr[p] += old.x; gi[p] += old.y;
        }
    }
    __syncthreads();

    int fi_[3], sg_[3];
    #pragma unroll
    for (int p = 0; p < 3; ++p) f_to_fi_sigma(p * 192 + c, fi_[p], sg_[p]);
    #pragma unroll
    for (int k = 0; k < SEG; ++k) {
        int t = k * 256 + tid;
        if (t < T_FRAMES) {
            float accx = 0.0f, accy = 0.0f;
            #pragma unroll
            for (int p = 0; p < 3; ++p) {
                float2 g0 = col[p * NBLK + t];
                float2 g1 = col[p * NBLK + t + FULLBLK];
                // qp = .zw of QFP, streamed coalesced from global
                float2 qp = base[2 * ((size_t)(p * 192 + c) * NBP + t + FULLBLK) + 1];
                float ur = g1.x - g0.x + qp.x;
                float ui = g1.y - g0.y + qp.y;
                unsigned ph = ((unsigned)fi_[p] * 128u * (unsigned)t) & 65535u;
                float frf = (float)ph * (1.0f / 65536.0f)
                          - (float)sg_[p] * (float)((128 * t) % MIN_WIN) * (1.0f / (float)MIN_WIN);
                frf -= rintf(frf);
                float sn, cs;
                __sincosf(TWOPI * frf, &sn, &cs);
                float vr = ur * cs - ui * sn;
                float vi = ur * sn + ui * cs;
                float wgt = (p == 0) ? 0.5f : -0.25f;
                accx = fmaf(wgt, vr, accx);
                accy = fmaf(wgt, vi, accy);
            }
            Sc[(size_t)c * SCP + t] = make_float2(accx, accy);
        }
    }
}

// 8 frames/block: power -> interp -> log -> DCT; fp64 atomic stats partials
__global__ __launch_bounds__(256) void k_cqt(const float2* __restrict__ Sc,
                                             float* __restrict__ cq,
                                             double* __restrict__ sums) {
    __shared__ float dctm[N_CQCC * N_BINS];  // 7680 B
    __shared__ float lg[8][N_BINS];
    __shared__ float cqv[8][N_CQCC];
    int tid = threadIdx.x;
    int tb = blockIdx.x * 8;
    for (int idx = tid; idx < N_CQCC * N_BINS; idx += 256) {
        int k = idx / N_BINS, b = idx - k * N_BINS;
        dctm[idx] = cosf((float)M_PI * (float)(k * (2 * b + 1)) / 192.0f);
    }
    int lt = tid >> 5, lane = tid & 31;
    int t = tb + lt;
    #pragma unroll
    for (int bb = 0; bb < 3; ++bb) {
        int b = lane + 32 * bb;
        float lv = 0.0f;
        if (t < T_FRAMES) {
            float2 lo = Sc[(size_t)(2 * b) * SCP + t];
            float2 hi = Sc[(size_t)(2 * b + 1) * SCP + t];
            float pl = lo.x * lo.x + lo.y * lo.y;
            float ph = hi.x * hi.x + hi.y * hi.y;
            float e    = (float)b / 24.0f;
            float fb   = 32.7f * exp2f(e);
            float idxf = fb / 8000.0f * 32768.0f;
            float alpha = idxf - (float)((int)idxf);
            float p = (1.0f - alpha) * pl + alpha * ph;
            lv = logf(fmaxf(p, 1e-8f));
        }
        lg[lt][b] = lv;
    }
    __syncthreads();
    if (tid < 8 * N_CQCC) {
        int lt2 = tid / N_CQCC, k = tid - lt2 * N_CQCC;
        int t2 = tb + lt2;
        float s = 0.0f;
        #pragma unroll 4
        for (int b = 0; b < N_BINS; ++b) s += dctm[k * N_BINS + b] * lg[lt2][b];
        cqv[lt2][k] = (t2 < T_FRAMES) ? s : 0.0f;
        if (t2 < T_FRAMES) cq[t2 * N_CQCC + k] = s;
    }
    __syncthreads();
    if (tid < N_CQCC) {
        double s1 = 0.0, s2 = 0.0;
        #pragma unroll
        for (int lt2 = 0; lt2 < 8; ++lt2) {
            if (tb + lt2 < T_FRAMES) {
                double v = (double)cqv[lt2][tid];
                s1 += v; s2 += v * v;
            }
        }
        atomicAdd(&sums[tid], s1);
        atomicAdd(&sums[N_CQCC + tid], s2);
    }
}

__device__ __forceinline__ int clampT(int v) {
    return v < 0 ? 0 : (v > T_FRAMES - 1 ? T_FRAMES - 1 : v);
}

// normalize + delta + delta-delta; mean/inv derived inline from fp64 sums
__global__ void k_final(const float* __restrict__ cq, const double* __restrict__ sums,
                        float* __restrict__ out) {
    int gid = blockIdx.x * blockDim.x + threadIdx.x;
    if (gid >= T_FRAMES * N_CQCC) return;
    int t = gid / N_CQCC;
    int k = gid - t * N_CQCC;
    double S1 = sums[k], S2 = sums[N_CQCC + k];
    double md = S1 / (double)T_FRAMES;
    double var = (S2 - S1 * md) / (double)(T_FRAMES - 1);
    double sd = sqrt(var > 0.0 ? var : 0.0);
    float m = (float)md;
    float iv = (float)(1.0 / (sd + 1e-8));
    float cv[9];
    #pragma unroll
    for (int j = 0; j < 9; ++j)
        cv[j] = (cq[clampT(t + j - 4) * N_CQCC + k] - m) * iv;
    float dv[5];
    #pragma unroll
    for (int o = -2; o <= 2; ++o) {
        int p = clampT(t + o);
        int h1 = clampT(p + 1) - t, l1 = clampT(p - 1) - t;
        int h2 = clampT(p + 2) - t, l2 = clampT(p - 2) - t;
        dv[o + 2] = ((cv[h1 + 4] - cv[l1 + 4]) + 2.0f * (cv[h2 + 4] - cv[l2 + 4])) * 0.1f;
    }
    out[t * 60 + k]      = cv[4];
    out[t * 60 + 20 + k] = dv[2];
    out[t * 60 + 40 + k] = (dv[3] - dv[1] + 2.0f * (dv[4] - dv[0])) * 0.1f;
}

extern "C" void kernel_launch(void* const* d_in, const int* in_sizes, int n_in,
                              void* d_out, int out_size, void* d_ws, size_t ws_size,
                              hipStream_t stream) {
    const float* wav = (const float*)d_in[0];
    float* out = (float*)d_out;
    char* ws = (char*)d_ws;
    float4* QFP  = (float4*)(ws + WS_QFP);
    float2* Sc   = (float2*)(ws + WS_SC);
    float*  cq   = (float*)(ws + WS_CQ);
    double* sums = (double*)(ws + WS_SUMS);

    k_chunk<<<dim3(NBP / BT, NF / FTW), 256, 0, stream>>>(wav, QFP);
    k_scan<<<F_COMP, 256, 0, stream>>>(QFP, Sc, sums);
    k_cqt<<<(T_FRAMES + 7) / 8, 256, 0, stream>>>(Sc, cq, sums);
    k_final<<<(T_FRAMES * N_CQCC + 255) / 256, 256, 0, stream>>>(cq, sums, out);
}

// Round 9
// 108.214 us; speedup vs baseline: 1.1284x; 1.0608x over previous
//
#include <hip/hip_runtime.h>
#include <math.h>

// ---- problem constants ----
#define WAV_N     262144
#define HOP       128
#define MIN_WIN   16699
#define LEFT      24418            // (65536 - 16699)/2
#define T_FRAMES  2049
#define N_BINS    96
#define N_CQCC    20
#define F_COMP    192              // 96 bins x {lo,hi}
#define NF        576              // 192 comps x 3 Hann planes
#define NBLK      2179             // 128-sample chunks covering padded signal
#define NBP       2240             // padded b-dim for QFP rows (= 70*32)
#define PARTLEN   59               // 16699 - 130*128
#define FULLBLK   130
#define XS_VALID  278843           // 2048*128 + 16699
#define TWOPI     6.283185307179586f

// ---- chunk kernel tiling: 1260 blocks (70 x 18), 256 thr = 32 f x 8 bg x 4 b ----
#define BT   32
#define FTW  32
#define AST  34                    // A_lds row stride: writes 2-way-free, reads 8B-aligned

// ---- workspace layout (bytes) ----
#define WS_QFP  0                  // 576*2240*16 = 20,643,840  float4(qf.re,qf.im,qp.re,qp.im)
#define WS_SC   20643840           // 192*2056*8  =  3,158,016  folded spectrum [c][t]
#define WS_CQ   23801856           // 2049*20*4   =    163,920
#define WS_SUMS 23965776           // 40 doubles
#define SCP     2056               // Sc row stride (float2 units)

// f = plane*192 + c; c = bin*2 + hi; replicate reference f32 arithmetic for floor()
__device__ __forceinline__ void f_to_fi_sigma(int f, int& fi, int& sigma) {
    int plane = f / 192;
    int c = f - plane * 192;
    int bin = c >> 1, hi = c & 1;
    float e    = (float)bin / 24.0f;
    float fb   = 32.7f * exp2f(e);
    float idxf = fb / 8000.0f * 32768.0f;
    fi = (int)idxf + hi;
    sigma = (plane == 0) ? 0 : (plane == 1 ? 1 : -1);
}

// QFP[f][b] = (qf, qp): qf = e^{-i w0} sum_{j<128} xs[128b+j] E[j][f], qp = j<59 version
// 1260-block geometry: 4.9 waves/SIMD (r6's 630 blocks gave 2.46 -> VALUBusy ~20%,
// latency-exposed; grid size, not per-thread work, was the k_chunk pole).
__global__ __launch_bounds__(256) void k_chunk(const float* __restrict__ wav,
                                               float4* __restrict__ QFP) {
    __shared__ float A_lds[128 * AST];             // 17,408 B
    int tid = threadIdx.x;
    int b0 = blockIdx.x * BT;
    int f0 = blockIdx.y * FTW;

    // stage full 32b x 128j tile: element m -> (bl = m>>7, j = m&127), s = 128*b0 + m
    {
        int sbase = 128 * b0;
        #pragma unroll
        for (int k = 0; k < 16; ++k) {
            int m = k * 256 + tid;
            int j = m & 127, bl = m >> 7;
            int s = sbase + m;
            float v = 0.0f;
            if (s < XS_VALID) {
                int w = s - 8350;                  // s + LEFT - 32768
                if (w < 0) w = -w;
                if (w >= WAV_N) w = 2 * WAV_N - 2 - w;
                v = wav[w];
            }
            A_lds[j * AST + bl] = v;
        }
    }

    int f  = f0 + (tid & 31);
    int bg = tid >> 5;                             // 0..7
    int bl0 = bg * 4;
    int bb = b0 + bl0;

    int fi, sg;
    f_to_fi_sigma(f, fi, sg);

    // rotator step D = e^{-2*pi*i*(fi/65536 - sg/W)}; anchor W = 1 at j=0 (exact)
    float Dr, Di;
    {
        float fr = (float)fi * (1.0f / 65536.0f) - (float)sg * (1.0f / (float)MIN_WIN);
        fr -= rintf(fr);
        float sn, cs; __sincosf(TWOPI * fr, &sn, &cs);
        Dr = cs; Di = -sn;
    }
    float Wr = 1.0f, Wi = 0.0f;

    float xr[4] = {0, 0, 0, 0}, xi[4] = {0, 0, 0, 0};
    float pr[4], pi[4];

    __syncthreads();

    #pragma unroll 4
    for (int j = 0; j < PARTLEN; ++j) {
        float2 a01 = *(const float2*)&A_lds[j * AST + bl0];
        float2 a23 = *(const float2*)&A_lds[j * AST + bl0 + 2];
        const float aa[4] = {a01.x, a01.y, a23.x, a23.y};
        #pragma unroll
        for (int i = 0; i < 4; ++i) {
            xr[i] = fmaf(aa[i], Wr, xr[i]);
            xi[i] = fmaf(aa[i], Wi, xi[i]);
        }
        float wr = Wr;
        Wr = wr * Dr - Wi * Di;
        Wi = wr * Di + Wi * Dr;
    }
    #pragma unroll
    for (int i = 0; i < 4; ++i) { pr[i] = xr[i]; pi[i] = xi[i]; }
    #pragma unroll 4
    for (int j = PARTLEN; j < 128; ++j) {
        float2 a01 = *(const float2*)&A_lds[j * AST + bl0];
        float2 a23 = *(const float2*)&A_lds[j * AST + bl0 + 2];
        const float aa[4] = {a01.x, a01.y, a23.x, a23.y};
        #pragma unroll
        for (int i = 0; i < 4; ++i) {
            xr[i] = fmaf(aa[i], Wr, xr[i]);
            xi[i] = fmaf(aa[i], Wi, xi[i]);
        }
        float wr = Wr;
        Wr = wr * Dr - Wi * Di;
        Wi = wr * Di + Wi * Dr;
    }

    // apply e^{-i w0(b,f)} and store (qf, qp) interleaved; b>=NBLK rows are pad (zeros)
    float4* dst = QFP + (size_t)f * NBP + bb;
    #pragma unroll
    for (int i = 0; i < 4; ++i) {
        int b = bb + i;
        unsigned ph = ((unsigned)fi * (unsigned)(LEFT + 128 * b)) & 65535u;
        float frf = (float)ph * (1.0f / 65536.0f)
                  - (float)sg * (float)((128 * b) % MIN_WIN) * (1.0f / (float)MIN_WIN);
        frf -= rintf(frf);
        float sn, cs; __sincosf(TWOPI * frf, &sn, &cs);
        dst[i] = make_float4(xr[i] * cs + xi[i] * sn,
                             xi[i] * cs - xr[i] * sn,
                             pr[i] * cs + pi[i] * sn,
                             pi[i] * cs - pr[i] * sn);
    }
}

// one block per component c: all 3 Hann-plane columns processed concurrently.
// U = G[t+130]-G[t]+qp[t+130]; rotate by e^{+i tau}; fold 0.5/-0.25/-0.25; Sc[c][t].
#define SEG 9                      // 256*9 >= 2179
__global__ __launch_bounds__(256) void k_scan(const float4* __restrict__ QFP,
                                              float2* __restrict__ Sc,
                                              double* __restrict__ sums) {
    __shared__ float2 col[3 * NBLK];   // 52,296 B
    __shared__ double2 wsum[3][4];
    int tid = threadIdx.x;
    int c = blockIdx.x;
    if (c == 0 && tid < 40) sums[tid] = 0.0;   // zero stats accumulators

    // load .xy (qf) of all 3 plane columns -- 27 independent strided loads
    const float2* base = (const float2*)QFP;
    #pragma unroll
    for (int p = 0; p < 3; ++p) {
        size_t foff = (size_t)(p * 192 + c) * NBP;
        #pragma unroll
        for (int k = 0; k < SEG; ++k) {
            int idx = k * 256 + tid;
            if (idx < NBLK) col[p * NBLK + idx] = base[2 * (foff + idx)];
        }
    }
    __syncthreads();

    int s0 = tid * SEG, s1 = min(s0 + SEG, NBLK);
    double sr[3] = {0, 0, 0}, si[3] = {0, 0, 0};
    #pragma unroll
    for (int p = 0; p < 3; ++p)
        for (int i = s0; i < s1; ++i) {
            sr[p] += col[p * NBLK + i].x;
            si[p] += col[p * NBLK + i].y;
        }
    double r[3], im[3];
    #pragma unroll
    for (int p = 0; p < 3; ++p) { r[p] = sr[p]; im[p] = si[p]; }
    #pragma unroll
    for (int off = 1; off < 64; off <<= 1) {
        #pragma unroll
        for (int p = 0; p < 3; ++p) {
            double prx = __shfl_up(r[p], off);
            double piy = __shfl_up(im[p], off);
            if ((tid & 63) >= off) { r[p] += prx; im[p] += piy; }
        }
    }
    if ((tid & 63) == 63) {
        #pragma unroll
        for (int p = 0; p < 3; ++p) wsum[p][tid >> 6] = make_double2(r[p], im[p]);
    }
    __syncthreads();
    int w = tid >> 6;
    double gr[3], gi[3];
    #pragma unroll
    for (int p = 0; p < 3; ++p) {
        double basr = 0.0, basi = 0.0;
        for (int ww = 0; ww < w; ++ww) { basr += wsum[p][ww].x; basi += wsum[p][ww].y; }
        gr[p] = basr + r[p] - sr[p];       // exclusive prefix at s0
        gi[p] = basi + im[p] - si[p];
    }
    for (int i = s0; i < s1; ++i) {
        #pragma unroll
        for (int p = 0; p < 3; ++p) {
            float2 old = col[p * NBLK + i];
            col[p * NBLK + i] = make_float2((float)gr[p], (float)gi[p]);
            gr[p] += old.x; gi[p] += old.y;
        }
    }
    __syncthreads();

    int fi_[3], sg_[3];
    #pragma unroll
    for (int p = 0; p < 3; ++p) f_to_fi_sigma(p * 192 + c, fi_[p], sg_[p]);
    #pragma unroll
    for (int k = 0; k < SEG; ++k) {
        int t = k * 256 + tid;
        if (t < T_FRAMES) {
            float accx = 0.0f, accy = 0.0f;
            #pragma unroll
            for (int p = 0; p < 3; ++p) {
                float2 g0 = col[p * NBLK + t];
                float2 g1 = col[p * NBLK + t + FULLBLK];
                float2 qp = base[2 * ((size_t)(p * 192 + c) * NBP + t + FULLBLK) + 1];
                float ur = g1.x - g0.x + qp.x;
                float ui = g1.y - g0.y + qp.y;
                unsigned ph = ((unsigned)fi_[p] * 128u * (unsigned)t) & 65535u;
                float frf = (float)ph * (1.0f / 65536.0f)
                          - (float)sg_[p] * (float)((128 * t) % MIN_WIN) * (1.0f / (float)MIN_WIN);
                frf -= rintf(frf);
                float sn, cs;
                __sincosf(TWOPI * frf, &sn, &cs);
                float vr = ur * cs - ui * sn;
                float vi = ur * sn + ui * cs;
                float wgt = (p == 0) ? 0.5f : -0.25f;
                accx = fmaf(wgt, vr, accx);
                accy = fmaf(wgt, vi, accy);
            }
            Sc[(size_t)c * SCP + t] = make_float2(accx, accy);
        }
    }
}

// 8 frames/block: power -> interp -> log -> DCT; fp64 atomic stats partials
__global__ __launch_bounds__(256) void k_cqt(const float2* __restrict__ Sc,
                                             float* __restrict__ cq,
                                             double* __restrict__ sums) {
    __shared__ float dctm[N_CQCC * N_BINS];  // 7680 B
    __shared__ float lg[8][N_BINS];
    __shared__ float cqv[8][N_CQCC];
    int tid = threadIdx.x;
    int tb = blockIdx.x * 8;
    for (int idx = tid; idx < N_CQCC * N_BINS; idx += 256) {
        int k = idx / N_BINS, b = idx - k * N_BINS;
        dctm[idx] = cosf((float)M_PI * (float)(k * (2 * b + 1)) / 192.0f);
    }
    int lt = tid >> 5, lane = tid & 31;
    int t = tb + lt;
    #pragma unroll
    for (int bb = 0; bb < 3; ++bb) {
        int b = lane + 32 * bb;
        float lv = 0.0f;
        if (t < T_FRAMES) {
            float2 lo = Sc[(size_t)(2 * b) * SCP + t];
            float2 hi = Sc[(size_t)(2 * b + 1) * SCP + t];
            float pl = lo.x * lo.x + lo.y * lo.y;
            float ph = hi.x * hi.x + hi.y * hi.y;
            float e    = (float)b / 24.0f;
            float fb   = 32.7f * exp2f(e);
            float idxf = fb / 8000.0f * 32768.0f;
            float alpha = idxf - (float)((int)idxf);
            float p = (1.0f - alpha) * pl + alpha * ph;
            lv = logf(fmaxf(p, 1e-8f));
        }
        lg[lt][b] = lv;
    }
    __syncthreads();
    if (tid < 8 * N_CQCC) {
        int lt2 = tid / N_CQCC, k = tid - lt2 * N_CQCC;
        int t2 = tb + lt2;
        float s = 0.0f;
        #pragma unroll 4
        for (int b = 0; b < N_BINS; ++b) s += dctm[k * N_BINS + b] * lg[lt2][b];
        cqv[lt2][k] = (t2 < T_FRAMES) ? s : 0.0f;
        if (t2 < T_FRAMES) cq[t2 * N_CQCC + k] = s;
    }
    __syncthreads();
    if (tid < N_CQCC) {
        double s1 = 0.0, s2 = 0.0;
        #pragma unroll
        for (int lt2 = 0; lt2 < 8; ++lt2) {
            if (tb + lt2 < T_FRAMES) {
                double v = (double)cqv[lt2][tid];
                s1 += v; s2 += v * v;
            }
        }
        atomicAdd(&sums[tid], s1);
        atomicAdd(&sums[N_CQCC + tid], s2);
    }
}

__device__ __forceinline__ int clampT(int v) {
    return v < 0 ? 0 : (v > T_FRAMES - 1 ? T_FRAMES - 1 : v);
}

// normalize + delta + delta-delta; mean/inv derived inline from fp64 sums
__global__ void k_final(const float* __restrict__ cq, const double* __restrict__ sums,
                        float* __restrict__ out) {
    int gid = blockIdx.x * blockDim.x + threadIdx.x;
    if (gid >= T_FRAMES * N_CQCC) return;
    int t = gid / N_CQCC;
    int k = gid - t * N_CQCC;
    double S1 = sums[k], S2 = sums[N_CQCC + k];
    double md = S1 / (double)T_FRAMES;
    double var = (S2 - S1 * md) / (double)(T_FRAMES - 1);
    double sd = sqrt(var > 0.0 ? var : 0.0);
    float m = (float)md;
    float iv = (float)(1.0 / (sd + 1e-8));
    float cv[9];
    #pragma unroll
    for (int j = 0; j < 9; ++j)
        cv[j] = (cq[clampT(t + j - 4) * N_CQCC + k] - m) * iv;
    float dv[5];
    #pragma unroll
    for (int o = -2; o <= 2; ++o) {
        int p = clampT(t + o);
        int h1 = clampT(p + 1) - t, l1 = clampT(p - 1) - t;
        int h2 = clampT(p + 2) - t, l2 = clampT(p - 2) - t;
        dv[o + 2] = ((cv[h1 + 4] - cv[l1 + 4]) + 2.0f * (cv[h2 + 4] - cv[l2 + 4])) * 0.1f;
    }
    out[t * 60 + k]      = cv[4];
    out[t * 60 + 20 + k] = dv[2];
    out[t * 60 + 40 + k] = (dv[3] - dv[1] + 2.0f * (dv[4] - dv[0])) * 0.1f;
}

extern "C" void kernel_launch(void* const* d_in, const int* in_sizes, int n_in,
                              void* d_out, int out_size, void* d_ws, size_t ws_size,
                              hipStream_t stream) {
    const float* wav = (const float*)d_in[0];
    float* out = (float*)d_out;
    char* ws = (char*)d_ws;
    float4* QFP  = (float4*)(ws + WS_QFP);
    float2* Sc   = (float2*)(ws + WS_SC);
    float*  cq   = (float*)(ws + WS_CQ);
    double* sums = (double*)(ws + WS_SUMS);

    k_chunk<<<dim3(NBP / BT, NF / FTW), 256, 0, stream>>>(wav, QFP);
    k_scan<<<F_COMP, 256, 0, stream>>>(QFP, Sc, sums);
    k_cqt<<<(T_FRAMES + 7) / 8, 256, 0, stream>>>(Sc, cq, sums);
    k_final<<<(T_FRAMES * N_CQCC + 255) / 256, 256, 0, stream>>>(cq, sums, out);
}

// Round 10
// 106.787 us; speedup vs baseline: 1.1434x; 1.0134x over previous
//
#include <hip/hip_runtime.h>
#include <math.h>

// ---- problem constants ----
#define WAV_N     262144
#define HOP       128
#define MIN_WIN   16699
#define LEFT      24418            // (65536 - 16699)/2
#define T_FRAMES  2049
#define N_BINS    96
#define N_CQCC    20
#define F_COMP    192              // 96 bins x {lo,hi}
#define NF        576              // 192 comps x 3 Hann planes
#define NBLK      2179             // 128-sample chunks covering padded signal
#define NBP       2240             // padded b-dim for QFP rows (= 70*32)
#define PARTLEN   59               // 16699 - 130*128
#define FULLBLK   130
#define XS_VALID  278843           // 2048*128 + 16699
#define TWOPI     6.283185307179586f

// ---- chunk kernel tiling: 1260 blocks (70 x 18), 256 thr = 32 f x 8 bg x 4 b ----
#define BT   32
#define FTW  32
#define AST  34                    // A_lds row stride

// ---- workspace layout (bytes) ----
#define WS_QFP  0                  // 576*2240*16 = 20,643,840  float4(qf.re,qf.im,qp.re,qp.im)
#define WS_V    20643840           // 576*2056*8  =  9,474,048  rotated V [f][t]
#define WS_CQ   30117888           // 2049*20*4   =    163,920
#define WS_SUMS 30281808           // 40 doubles
#define VTP     2056               // V row stride (float2 units)

// f = plane*192 + c; c = bin*2 + hi; replicate reference f32 arithmetic for floor()
__device__ __forceinline__ void f_to_fi_sigma(int f, int& fi, int& sigma) {
    int plane = f / 192;
    int c = f - plane * 192;
    int bin = c >> 1, hi = c & 1;
    float e    = (float)bin / 24.0f;
    float fb   = 32.7f * exp2f(e);
    float idxf = fb / 8000.0f * 32768.0f;
    fi = (int)idxf + hi;
    sigma = (plane == 0) ? 0 : (plane == 1 ? 1 : -1);
}

// QFP[f][b] = (qf, qp): qf = e^{-i w0} sum_{j<128} xs[128b+j] E[j][f], qp = j<59 version
__global__ __launch_bounds__(256) void k_chunk(const float* __restrict__ wav,
                                               float4* __restrict__ QFP) {
    __shared__ float A_lds[128 * AST];             // 17,408 B
    int tid = threadIdx.x;
    int b0 = blockIdx.x * BT;
    int f0 = blockIdx.y * FTW;

    // stage full 32b x 128j tile
    {
        int sbase = 128 * b0;
        #pragma unroll
        for (int k = 0; k < 16; ++k) {
            int m = k * 256 + tid;
            int j = m & 127, bl = m >> 7;
            int s = sbase + m;
            float v = 0.0f;
            if (s < XS_VALID) {
                int w = s - 8350;                  // s + LEFT - 32768
                if (w < 0) w = -w;
                if (w >= WAV_N) w = 2 * WAV_N - 2 - w;
                v = wav[w];
            }
            A_lds[j * AST + bl] = v;
        }
    }

    int f  = f0 + (tid & 31);
    int bg = tid >> 5;                             // 0..7
    int bl0 = bg * 4;
    int bb = b0 + bl0;

    int fi, sg;
    f_to_fi_sigma(f, fi, sg);

    // rotator step D = e^{-2*pi*i*(fi/65536 - sg/W)}; anchor W = 1 at j=0 (exact)
    float Dr, Di;
    {
        float fr = (float)fi * (1.0f / 65536.0f) - (float)sg * (1.0f / (float)MIN_WIN);
        fr -= rintf(fr);
        float sn, cs; __sincosf(TWOPI * fr, &sn, &cs);
        Dr = cs; Di = -sn;
    }
    float Wr = 1.0f, Wi = 0.0f;

    float xr[4] = {0, 0, 0, 0}, xi[4] = {0, 0, 0, 0};
    float pr[4], pi[4];

    __syncthreads();

    #pragma unroll 4
    for (int j = 0; j < PARTLEN; ++j) {
        float2 a01 = *(const float2*)&A_lds[j * AST + bl0];
        float2 a23 = *(const float2*)&A_lds[j * AST + bl0 + 2];
        const float aa[4] = {a01.x, a01.y, a23.x, a23.y};
        #pragma unroll
        for (int i = 0; i < 4; ++i) {
            xr[i] = fmaf(aa[i], Wr, xr[i]);
            xi[i] = fmaf(aa[i], Wi, xi[i]);
        }
        float wr = Wr;
        Wr = wr * Dr - Wi * Di;
        Wi = wr * Di + Wi * Dr;
    }
    #pragma unroll
    for (int i = 0; i < 4; ++i) { pr[i] = xr[i]; pi[i] = xi[i]; }
    #pragma unroll 4
    for (int j = PARTLEN; j < 128; ++j) {
        float2 a01 = *(const float2*)&A_lds[j * AST + bl0];
        float2 a23 = *(const float2*)&A_lds[j * AST + bl0 + 2];
        const float aa[4] = {a01.x, a01.y, a23.x, a23.y};
        #pragma unroll
        for (int i = 0; i < 4; ++i) {
            xr[i] = fmaf(aa[i], Wr, xr[i]);
            xi[i] = fmaf(aa[i], Wi, xi[i]);
        }
        float wr = Wr;
        Wr = wr * Dr - Wi * Di;
        Wi = wr * Di + Wi * Dr;
    }

    float4* dst = QFP + (size_t)f * NBP + bb;
    #pragma unroll
    for (int i = 0; i < 4; ++i) {
        int b = bb + i;
        unsigned ph = ((unsigned)fi * (unsigned)(LEFT + 128 * b)) & 65535u;
        float frf = (float)ph * (1.0f / 65536.0f)
                  - (float)sg * (float)((128 * b) % MIN_WIN) * (1.0f / (float)MIN_WIN);
        frf -= rintf(frf);
        float sn, cs; __sincosf(TWOPI * frf, &sn, &cs);
        dst[i] = make_float4(xr[i] * cs + xi[i] * sn,
                             xi[i] * cs - xr[i] * sn,
                             pr[i] * cs + pi[i] * sn,
                             pi[i] * cs - pr[i] * sn);
    }
}

// one block per f (576 blocks x 512 thr, 4.5 waves/SIMD): LDS-resident float4 column,
// fp64 scan of .xy, U = G[t+130]-G[t]+qp[t+130] (qp = .zw, LDS), rotate, write V[f][t].
#define SEG 5                      // 512*5 = 2560 >= 2179
__global__ __launch_bounds__(512) void k_scan(const float4* __restrict__ QFP,
                                              float2* __restrict__ V,
                                              double* __restrict__ sums) {
    __shared__ float4 col[NBLK];       // 34,864 B
    __shared__ double2 wsum[8];
    int tid = threadIdx.x;
    int f = blockIdx.x;
    if (f == 0 && tid < 40) sums[tid] = 0.0;   // zero stats accumulators

    const float4* g = QFP + (size_t)f * NBP;
    #pragma unroll
    for (int k = 0; k < SEG; ++k) {
        int idx = k * 512 + tid;
        if (idx < NBLK) col[idx] = g[idx];
    }
    __syncthreads();

    int s0 = tid * SEG, s1 = min(s0 + SEG, NBLK);
    double sr = 0.0, si = 0.0;
    for (int i = s0; i < s1; ++i) { sr += col[i].x; si += col[i].y; }
    double r = sr, im = si;
    #pragma unroll
    for (int off = 1; off < 64; off <<= 1) {
        double prx = __shfl_up(r, off);
        double piy = __shfl_up(im, off);
        if ((tid & 63) >= off) { r += prx; im += piy; }
    }
    if ((tid & 63) == 63) wsum[tid >> 6] = make_double2(r, im);
    __syncthreads();
    double basr = 0.0, basi = 0.0;
    int w = tid >> 6;
    for (int ww = 0; ww < w; ++ww) { basr += wsum[ww].x; basi += wsum[ww].y; }
    double gr = basr + r - sr, gi = basi + im - si;   // exclusive prefix at s0
    for (int i = s0; i < s1; ++i) {
        float qx = col[i].x, qy = col[i].y;
        col[i].x = (float)gr; col[i].y = (float)gi;
        gr += qx; gi += qy;
    }
    __syncthreads();

    int fi_, sg_; f_to_fi_sigma(f, fi_, sg_);
    float2* vrow = V + (size_t)f * VTP;
    #pragma unroll
    for (int k = 0; k < SEG; ++k) {
        int t = k * 512 + tid;
        if (t < T_FRAMES) {
            float4 ca = col[t];
            float4 cb = col[t + FULLBLK];
            float ur = cb.x - ca.x + cb.z;
            float ui = cb.y - ca.y + cb.w;
            unsigned ph = ((unsigned)fi_ * 128u * (unsigned)t) & 65535u;
            float frf = (float)ph * (1.0f / 65536.0f)
                      - (float)sg_ * (float)((128 * t) % MIN_WIN) * (1.0f / (float)MIN_WIN);
            frf -= rintf(frf);
            float sn, cs;
            __sincosf(TWOPI * frf, &sn, &cs);
            vrow[t] = make_float2(ur * cs - ui * sn, ur * sn + ui * cs);
        }
    }
}

// 16 frames/block (129 blocks): fold 3 planes (coalesced V reads along t) -> power
// -> interp -> log -> DCT -> fp64 atomic stats partials
#define TF16 16
__global__ __launch_bounds__(256) void k_cqt(const float2* __restrict__ V,
                                             float* __restrict__ cq,
                                             double* __restrict__ sums) {
    __shared__ float dctm[N_CQCC * N_BINS];     // 7680 B
    __shared__ float2 sc[F_COMP * TF16];        // [c][tl], 24,576 B
    __shared__ float lg[N_BINS * TF16];         // [b][tl], 6144 B
    __shared__ float cqv[N_CQCC * TF16];        // [k][tl], 1280 B
    int tid = threadIdx.x;
    int tb = blockIdx.x * TF16;
    for (int idx = tid; idx < N_CQCC * N_BINS; idx += 256) {
        int k = idx / N_BINS, b = idx - k * N_BINS;
        dctm[idx] = cosf((float)M_PI * (float)(k * (2 * b + 1)) / 192.0f);
    }
    // fold: idx = c*16 + tl; reads of V rows contiguous along t (128 B per row chunk)
    for (int idx = tid; idx < F_COMP * TF16; idx += 256) {
        int c = idx >> 4, tl = idx & 15;
        int t = tb + tl;
        float2 v = make_float2(0.f, 0.f);
        if (t < T_FRAMES) {
            float2 v0 = V[(size_t)c * VTP + t];
            float2 v1 = V[(size_t)(192 + c) * VTP + t];
            float2 v2 = V[(size_t)(384 + c) * VTP + t];
            v = make_float2(0.5f * v0.x - 0.25f * (v1.x + v2.x),
                            0.5f * v0.y - 0.25f * (v1.y + v2.y));
        }
        sc[idx] = v;
    }
    __syncthreads();
    for (int idx = tid; idx < N_BINS * TF16; idx += 256) {
        int b = idx >> 4, tl = idx & 15;
        float2 lo = sc[(2 * b) * TF16 + tl];
        float2 hi = sc[(2 * b + 1) * TF16 + tl];
        float pl = lo.x * lo.x + lo.y * lo.y;
        float ph = hi.x * hi.x + hi.y * hi.y;
        float e    = (float)b / 24.0f;
        float fb   = 32.7f * exp2f(e);
        float idxf = fb / 8000.0f * 32768.0f;
        float alpha = idxf - (float)((int)idxf);
        float p = (1.0f - alpha) * pl + alpha * ph;
        lg[idx] = logf(fmaxf(p, 1e-8f));
    }
    __syncthreads();
    for (int idx = tid; idx < N_CQCC * TF16; idx += 256) {
        int k = idx >> 4, tl = idx & 15;
        int t = tb + tl;
        float s = 0.0f;
        #pragma unroll 4
        for (int b = 0; b < N_BINS; ++b) s += dctm[k * N_BINS + b] * lg[b * TF16 + tl];
        cqv[idx] = (t < T_FRAMES) ? s : 0.0f;
        if (t < T_FRAMES) cq[t * N_CQCC + k] = s;
    }
    __syncthreads();
    if (tid < N_CQCC) {
        double s1 = 0.0, s2 = 0.0;
        #pragma unroll
        for (int tl = 0; tl < TF16; ++tl) {
            if (tb + tl < T_FRAMES) {
                double v = (double)cqv[tid * TF16 + tl];
                s1 += v; s2 += v * v;
            }
        }
        atomicAdd(&sums[tid], s1);
        atomicAdd(&sums[N_CQCC + tid], s2);
    }
}

__device__ __forceinline__ int clampT(int v) {
    return v < 0 ? 0 : (v > T_FRAMES - 1 ? T_FRAMES - 1 : v);
}

// normalize + delta + delta-delta; mean/inv derived inline from fp64 sums
__global__ void k_final(const float* __restrict__ cq, const double* __restrict__ sums,
                        float* __restrict__ out) {
    int gid = blockIdx.x * blockDim.x + threadIdx.x;
    if (gid >= T_FRAMES * N_CQCC) return;
    int t = gid / N_CQCC;
    int k = gid - t * N_CQCC;
    double S1 = sums[k], S2 = sums[N_CQCC + k];
    double md = S1 / (double)T_FRAMES;
    double var = (S2 - S1 * md) / (double)(T_FRAMES - 1);
    double sd = sqrt(var > 0.0 ? var : 0.0);
    float m = (float)md;
    float iv = (float)(1.0 / (sd + 1e-8));
    float cv[9];
    #pragma unroll
    for (int j = 0; j < 9; ++j)
        cv[j] = (cq[clampT(t + j - 4) * N_CQCC + k] - m) * iv;
    float dv[5];
    #pragma unroll
    for (int o = -2; o <= 2; ++o) {
        int p = clampT(t + o);
        int h1 = clampT(p + 1) - t, l1 = clampT(p - 1) - t;
        int h2 = clampT(p + 2) - t, l2 = clampT(p - 2) - t;
        dv[o + 2] = ((cv[h1 + 4] - cv[l1 + 4]) + 2.0f * (cv[h2 + 4] - cv[l2 + 4])) * 0.1f;
    }
    out[t * 60 + k]      = cv[4];
    out[t * 60 + 20 + k] = dv[2];
    out[t * 60 + 40 + k] = (dv[3] - dv[1] + 2.0f * (dv[4] - dv[0])) * 0.1f;
}

extern "C" void kernel_launch(void* const* d_in, const int* in_sizes, int n_in,
                              void* d_out, int out_size, void* d_ws, size_t ws_size,
                              hipStream_t stream) {
    const float* wav = (const float*)d_in[0];
    float* out = (float*)d_out;
    char* ws = (char*)d_ws;
    float4* QFP  = (float4*)(ws + WS_QFP);
    float2* V    = (float2*)(ws + WS_V);
    float*  cq   = (float*)(ws + WS_CQ);
    double* sums = (double*)(ws + WS_SUMS);

    k_chunk<<<dim3(NBP / BT, NF / FTW), 256, 0, stream>>>(wav, QFP);
    k_scan<<<NF, 512, 0, stream>>>(QFP, V, sums);
    k_cqt<<<(T_FRAMES + TF16 - 1) / TF16, 256, 0, stream>>>(V, cq, sums);
    k_final<<<(T_FRAMES * N_CQCC + 255) / 256, 256, 0, stream>>>(cq, sums, out);
}